// Round 5
// baseline (301.986 us; speedup 1.0000x reference)
//
#include <hip/hip_runtime.h>
#include <math.h>

#define N_NODES 8192
#define N_EDGES 65536
#define F_IN    512
#define HID1    4096
#define HID2    1024
#define F_OUT   10
#define H3_STRIDE 16
#define W3S_STRIDE 1032   // bf16 elems per padded W3 row (16 rows)

typedef __bf16 bf16x8 __attribute__((ext_vector_type(8)));
typedef float floatx4 __attribute__((ext_vector_type(4)));

static __device__ __forceinline__ unsigned short f2bf(float f) {
    union { float f; unsigned u; } v; v.f = f;
    unsigned r = v.u + 0x7fffu + ((v.u >> 16) & 1u);   // RNE
    return (unsigned short)(r >> 16);
}
static __device__ __forceinline__ float bf2f(unsigned short u) {
    union { unsigned u; float f; } v; v.u = ((unsigned)u) << 16;
    return v.f;
}

// ---------------------------------------------------------------------------
// hist+scan (one block): deg[] = in-edge count via LDS histogram, then
// exclusive scan -> row_ptr, and cnt[] zeroing. Replaces memset+deg+scan.
// ---------------------------------------------------------------------------
__global__ __launch_bounds__(1024) void hist_scan_kernel(
        const int* __restrict__ ei, int* __restrict__ deg,
        int* __restrict__ row_ptr, int* __restrict__ cnt) {
    __shared__ int hist[N_NODES];        // 32 KB
    __shared__ int sums[1024];
    int t = threadIdx.x;
#pragma unroll
    for (int i = 0; i < 8; i++) hist[t + i * 1024] = 0;
    __syncthreads();
#pragma unroll
    for (int i = 0; i < 64; i++) {
        int d = ei[N_EDGES + i * 1024 + t];
        atomicAdd(&hist[d], 1);
    }
    __syncthreads();
    int base = t * 8;
    int local[8], run = 0;
#pragma unroll
    for (int i = 0; i < 8; i++) {
        int dv = hist[base + i];
        deg[base + i] = dv;
        cnt[base + i] = 0;
        local[i] = run; run += dv;
    }
    sums[t] = run;
    __syncthreads();
    for (int off = 1; off < 1024; off <<= 1) {
        int val = (t >= off) ? sums[t - off] : 0;
        __syncthreads();
        sums[t] += val;
        __syncthreads();
    }
    int offset = (t == 0) ? 0 : sums[t - 1];
#pragma unroll
    for (int i = 0; i < 8; i++) row_ptr[base + i] = offset + local[i];
    if (t == 1023) row_ptr[N_NODES] = sums[1023];
}

__global__ void fill_kernel(const int* __restrict__ ei, const int* __restrict__ deg,
                            const int* __restrict__ row_ptr, int* __restrict__ cnt,
                            int* __restrict__ csr_src, float* __restrict__ csr_w) {
    int e = blockIdx.x * blockDim.x + threadIdx.x;
    if (e < N_EDGES) {
        int s = ei[e];
        int d = ei[N_EDGES + e];
        int slot = row_ptr[d] + atomicAdd(&cnt[d], 1);
        csr_src[slot] = s;
        csr_w[slot] = rsqrtf((float)((deg[s] + 1) * (deg[d] + 1)));
    }
}

// ---------------------------------------------------------------------------
// prep: xcvt (blocks 0..4095) + W1 transpose (4096..6143) + W2 transpose
// (6144..10239), one launch.
// ---------------------------------------------------------------------------
static __device__ __forceinline__ void transpose_body(
        const float* __restrict__ W, unsigned short* __restrict__ Wt,
        int K, int N, int k0, int n0, int tid, float (*t)[33]) {
    int c = tid & 31, r8 = tid >> 5;
#pragma unroll
    for (int i = 0; i < 4; i++) {
        int r = r8 + i * 8;
        t[r][c] = W[(size_t)(k0 + r) * N + n0 + c];
    }
    __syncthreads();
#pragma unroll
    for (int i = 0; i < 4; i++) {
        int r = r8 + i * 8;
        Wt[(size_t)(n0 + r) * K + k0 + c] = f2bf(t[c][r]);
    }
}

__global__ __launch_bounds__(256) void prep_kernel(
        const float* __restrict__ x, unsigned short* __restrict__ xb,
        const float* __restrict__ W1, unsigned short* __restrict__ W1t,
        const float* __restrict__ W2, unsigned short* __restrict__ W2t) {
    __shared__ float t[32][33];
    int b = blockIdx.x, tid = threadIdx.x;
    if (b < 4096) {
        int i = b * 256 + tid;
        float4 a = ((const float4*)x)[i];
        ushort4 o;
        o.x = f2bf(a.x); o.y = f2bf(a.y); o.z = f2bf(a.z); o.w = f2bf(a.w);
        ((ushort4*)xb)[i] = o;
    } else if (b < 6144) {
        int bb = b - 4096;                       // W1: K=512, N=4096
        transpose_body(W1, W1t, F_IN, HID1, (bb >> 7) * 32, (bb & 127) * 32, tid, t);
    } else {
        int bb = b - 6144;                       // W2: K=4096, N=1024
        transpose_body(W2, W2t, HID1, HID2, (bb >> 5) * 32, (bb & 31) * 32, tid, t);
    }
}

// ---------------------------------------------------------------------------
// agg1: agg_x[v,:] = sum_e w_e*xb[src,:] + xb[v,:]/(deg+1) -> bf16
// ---------------------------------------------------------------------------
__global__ __launch_bounds__(256) void agg1_kernel(
        const unsigned short* __restrict__ xb, const int* __restrict__ row_ptr,
        const int* __restrict__ csr_src, const float* __restrict__ csr_w,
        const int* __restrict__ deg, unsigned short* __restrict__ out) {
    int v = blockIdx.x * 2 + (threadIdx.x >> 7);
    int t = threadIdx.x & 127;
    const ushort4* x4 = (const ushort4*)xb;    // row stride 128
    float sw = 1.0f / (float)(deg[v] + 1);
    ushort4 a = x4[(size_t)v * 128 + t];
    float ax = sw * bf2f(a.x), ay = sw * bf2f(a.y), az = sw * bf2f(a.z), aw = sw * bf2f(a.w);
    int e = row_ptr[v], end = row_ptr[v + 1];
    for (; e + 2 <= end; e += 2) {
        int s0 = csr_src[e], s1 = csr_src[e + 1];
        float w0 = csr_w[e], w1 = csr_w[e + 1];
        ushort4 b0 = x4[(size_t)s0 * 128 + t];
        ushort4 b1 = x4[(size_t)s1 * 128 + t];
        ax += w0 * bf2f(b0.x) + w1 * bf2f(b1.x);
        ay += w0 * bf2f(b0.y) + w1 * bf2f(b1.y);
        az += w0 * bf2f(b0.z) + w1 * bf2f(b1.z);
        aw += w0 * bf2f(b0.w) + w1 * bf2f(b1.w);
    }
    if (e < end) {
        int s = csr_src[e];
        float w = csr_w[e];
        ushort4 b = x4[(size_t)s * 128 + t];
        ax += w * bf2f(b.x); ay += w * bf2f(b.y); az += w * bf2f(b.z); aw += w * bf2f(b.w);
    }
    ushort4 o;
    o.x = f2bf(ax); o.y = f2bf(ay); o.z = f2bf(az); o.w = f2bf(aw);
    ((ushort4*)out)[(size_t)v * 128 + t] = o;
}

// ---------------------------------------------------------------------------
// agg2: relu(sum_e w_e*h[src,:] + h[v,:]/(deg+1) + b2) -> bf16
// ---------------------------------------------------------------------------
__global__ __launch_bounds__(256) void agg2_kernel(
        const unsigned short* __restrict__ h, const int* __restrict__ row_ptr,
        const int* __restrict__ csr_src, const float* __restrict__ csr_w,
        const int* __restrict__ deg, const float* __restrict__ bias,
        unsigned short* __restrict__ out) {
    int v = blockIdx.x;
    int t = threadIdx.x;
    const ushort4* h4 = (const ushort4*)h;     // row stride 256
    float sw = 1.0f / (float)(deg[v] + 1);
    ushort4 a = h4[(size_t)v * 256 + t];
    float ax = sw * bf2f(a.x), ay = sw * bf2f(a.y), az = sw * bf2f(a.z), aw = sw * bf2f(a.w);
    int e = row_ptr[v], end = row_ptr[v + 1];
    for (; e + 2 <= end; e += 2) {
        int s0 = csr_src[e], s1 = csr_src[e + 1];
        float w0 = csr_w[e], w1 = csr_w[e + 1];
        ushort4 b0 = h4[(size_t)s0 * 256 + t];
        ushort4 b1 = h4[(size_t)s1 * 256 + t];
        ax += w0 * bf2f(b0.x) + w1 * bf2f(b1.x);
        ay += w0 * bf2f(b0.y) + w1 * bf2f(b1.y);
        az += w0 * bf2f(b0.z) + w1 * bf2f(b1.z);
        aw += w0 * bf2f(b0.w) + w1 * bf2f(b1.w);
    }
    if (e < end) {
        int s = csr_src[e];
        float w = csr_w[e];
        ushort4 b = h4[(size_t)s * 256 + t];
        ax += w * bf2f(b.x); ay += w * bf2f(b.y); az += w * bf2f(b.z); aw += w * bf2f(b.w);
    }
    float4 bb = ((const float4*)bias)[t];
    ushort4 o;
    o.x = f2bf(fmaxf(ax + bb.x, 0.0f)); o.y = f2bf(fmaxf(ay + bb.y, 0.0f));
    o.z = f2bf(fmaxf(az + bb.z, 0.0f)); o.w = f2bf(fmaxf(aw + bb.w, 0.0f));
    ((ushort4*)out)[(size_t)v * 256 + t] = o;
}

// ---------------------------------------------------------------------------
// MFMA bf16 GEMM: C[M,N] = A[M,K] @ Bt[N,K]^T (+bias,relu)
// 128x128 tile, BK=64, XOR-swizzled LDS (conflict-free), XCD-aware swizzle.
// ---------------------------------------------------------------------------
template <bool OUT_BF16, bool BIAS, bool RELU>
__global__ __launch_bounds__(256) void gemm_mfma_kernel(
        const unsigned short* __restrict__ A,   // [M,K] bf16
        const unsigned short* __restrict__ Bt,  // [N,K] bf16
        const float* __restrict__ bias,         // [N] or null
        void* __restrict__ C,                   // [M,N] bf16 or f32
        int M, int N, int K) {
    __shared__ unsigned short As[128 * 64];
    __shared__ unsigned short Bs[128 * 64];
    int tid = threadIdx.x;
    int wave = tid >> 6, lane = tid & 63;
    int wm = wave >> 1, wn = wave & 1;
    int GN = N >> 7;
    int b = blockIdx.x;
    int ntile = (b >> 3) % GN;
    int mtile = ((b >> 3) / GN) * 8 + (b & 7);
    int m0 = mtile * 128, n0 = ntile * 128;
    int lrow = lane & 15, lquad = lane >> 4;

    floatx4 acc[4][4] = {};

    for (int k0 = 0; k0 < K; k0 += 64) {
#pragma unroll
        for (int j = 0; j < 4; j++) {
            int idx = j * 256 + tid;            // LDS 16B-slot 0..1023
            int r = idx >> 3;                   // row 0..127
            int kc = (idx & 7) ^ (r & 7);       // XOR swizzle on source chunk
            __builtin_amdgcn_global_load_lds(
                (const __attribute__((address_space(1))) void*)(A + (size_t)(m0 + r) * K + k0 + kc * 8),
                (__attribute__((address_space(3))) void*)(&As[idx * 8]), 16, 0, 0);
            __builtin_amdgcn_global_load_lds(
                (const __attribute__((address_space(1))) void*)(Bt + (size_t)(n0 + r) * K + k0 + kc * 8),
                (__attribute__((address_space(3))) void*)(&Bs[idx * 8]), 16, 0, 0);
        }
        __syncthreads();
#pragma unroll
        for (int kk = 0; kk < 2; kk++) {
            bf16x8 af[4], bfr[4];
#pragma unroll
            for (int mt = 0; mt < 4; mt++) {
                int R = wm * 64 + mt * 16 + lrow;
                int c = kk * 4 + lquad;
                af[mt] = *(const bf16x8*)&As[(R * 8 + (c ^ (R & 7))) * 8];
            }
#pragma unroll
            for (int nt = 0; nt < 4; nt++) {
                int R = wn * 64 + nt * 16 + lrow;
                int c = kk * 4 + lquad;
                bfr[nt] = *(const bf16x8*)&Bs[(R * 8 + (c ^ (R & 7))) * 8];
            }
#pragma unroll
            for (int mt = 0; mt < 4; mt++)
#pragma unroll
                for (int nt = 0; nt < 4; nt++)
                    acc[mt][nt] = __builtin_amdgcn_mfma_f32_16x16x32_bf16(
                        af[mt], bfr[nt], acc[mt][nt], 0, 0, 0);
        }
        __syncthreads();
    }

#pragma unroll
    for (int mt = 0; mt < 4; mt++) {
#pragma unroll
        for (int nt = 0; nt < 4; nt++) {
            int col = n0 + wn * 64 + nt * 16 + lrow;
            float bv = BIAS ? bias[col] : 0.0f;
#pragma unroll
            for (int r = 0; r < 4; r++) {
                int row = m0 + wm * 64 + mt * 16 + lquad * 4 + r;
                float v = acc[mt][nt][r] + bv;
                if (RELU) v = fmaxf(v, 0.0f);
                if (OUT_BF16)
                    ((unsigned short*)C)[(size_t)row * N + col] = f2bf(v);
                else
                    ((float*)C)[(size_t)row * N + col] = v;
            }
        }
    }
}

// ---------------------------------------------------------------------------
// GEMM3 via MFMA: H3[8192,16] = agg2b[8192,1024](bf16) @ W3pad[1024,16]
// W3 transposed to LDS [16][1032] bf16 (cols 10..15 zero); A-frags straight
// from global (agg2b rows are already MFMA-A layout). 4 waves = 64 rows/blk.
// ---------------------------------------------------------------------------
__global__ __launch_bounds__(256) void gemm3_mfma_kernel(
        const unsigned short* __restrict__ A,   // [8192,1024] bf16
        const float* __restrict__ W3,           // [1024,10] f32
        float* __restrict__ H3) {               // [8192,16] f32
    __shared__ unsigned short w3s[16 * W3S_STRIDE];   // ~33 KB
    int tid = threadIdx.x;
    for (int i = tid; i < 16 * W3S_STRIDE; i += 256) w3s[i] = 0;
    __syncthreads();
    for (int i = tid; i < HID2 * F_OUT; i += 256) {
        int k = i / F_OUT, c = i % F_OUT;
        w3s[c * W3S_STRIDE + k] = f2bf(W3[i]);
    }
    __syncthreads();
    int wave = tid >> 6, lane = tid & 63;
    int lrow = lane & 15, lquad = lane >> 4;
    int m0 = (blockIdx.x * 4 + wave) * 16;
    floatx4 acc = {};
    const unsigned short* arow = A + (size_t)(m0 + lrow) * HID2 + lquad * 8;
#pragma unroll
    for (int kk = 0; kk < 32; kk++) {
        bf16x8 af = *(const bf16x8*)(arow + kk * 32);
        bf16x8 bf = *(const bf16x8*)&w3s[lrow * W3S_STRIDE + kk * 32 + lquad * 8];
        acc = __builtin_amdgcn_mfma_f32_16x16x32_bf16(af, bf, acc, 0, 0, 0);
    }
#pragma unroll
    for (int r = 0; r < 4; r++)
        H3[(size_t)(m0 + lquad * 4 + r) * H3_STRIDE + lrow] = acc[r];
}

// ---------------------------------------------------------------------------
// Final: aggregate h3 (stride 16), add b3, log_softmax per node.
// ---------------------------------------------------------------------------
__global__ void final_kernel(const float* __restrict__ h3, const int* __restrict__ row_ptr,
                             const int* __restrict__ csr_src, const float* __restrict__ csr_w,
                             const int* __restrict__ deg, const float* __restrict__ b3,
                             float* __restrict__ out) {
    int v = blockIdx.x * blockDim.x + threadIdx.x;
    if (v >= N_NODES) return;
    const float4* h4 = (const float4*)h3;      // 4 float4 per row; first 3 used
    float sw = 1.0f / (float)(deg[v] + 1);
    float a[12];
    *(float4*)&a[0] = h4[v * 4];
    *(float4*)&a[4] = h4[v * 4 + 1];
    *(float4*)&a[8] = h4[v * 4 + 2];
    float acc[F_OUT];
#pragma unroll
    for (int c = 0; c < F_OUT; c++) acc[c] = b3[c] + sw * a[c];
    int end = row_ptr[v + 1];
    for (int e = row_ptr[v]; e < end; e++) {
        int s = csr_src[e];
        float w = csr_w[e];
        float bsrc[12];
        *(float4*)&bsrc[0] = h4[s * 4];
        *(float4*)&bsrc[4] = h4[s * 4 + 1];
        *(float4*)&bsrc[8] = h4[s * 4 + 2];
#pragma unroll
        for (int c = 0; c < F_OUT; c++) acc[c] += w * bsrc[c];
    }
    float m = acc[0];
#pragma unroll
    for (int c = 1; c < F_OUT; c++) m = fmaxf(m, acc[c]);
    float ssum = 0.0f;
#pragma unroll
    for (int c = 0; c < F_OUT; c++) ssum += expf(acc[c] - m);
    float l = logf(ssum);
#pragma unroll
    for (int c = 0; c < F_OUT; c++) out[v * F_OUT + c] = acc[c] - m - l;
}

// ---------------------------------------------------------------------------
// Launch
// ---------------------------------------------------------------------------
extern "C" void kernel_launch(void* const* d_in, const int* in_sizes, int n_in,
                              void* d_out, int out_size, void* d_ws, size_t ws_size,
                              hipStream_t stream) {
    const float* x  = (const float*)d_in[0];
    const float* W1 = (const float*)d_in[1];
    const float* b1 = (const float*)d_in[2];
    const float* W2 = (const float*)d_in[3];
    const float* b2 = (const float*)d_in[4];
    const float* W3 = (const float*)d_in[5];
    const float* b3 = (const float*)d_in[6];
    const int*   ei = (const int*)d_in[7];
    float* out = (float*)d_out;

    char* p = (char*)d_ws;
    int*   deg     = (int*)p;    p += N_NODES * 4;
    int*   cnt     = (int*)p;    p += N_NODES * 4;
    int*   row_ptr = (int*)p;    p += 33024;
    int*   csr_src = (int*)p;    p += N_EDGES * 4;
    float* csr_w   = (float*)p;  p += N_EDGES * 4;
    float* h3      = (float*)p;  p += N_NODES * H3_STRIDE * 4;
    unsigned short* xb    = (unsigned short*)p; p += (size_t)N_NODES * F_IN * 2;
    unsigned short* agg_x = (unsigned short*)p; p += (size_t)N_NODES * F_IN * 2;
    unsigned short* W1t   = (unsigned short*)p; p += (size_t)HID1 * F_IN * 2;
    unsigned short* W2t   = (unsigned short*)p; p += (size_t)HID2 * HID1 * 2;
    unsigned short* h1    = (unsigned short*)p; p += (size_t)N_NODES * HID1 * 2;
    unsigned short* h2pre = (unsigned short*)p; p += (size_t)N_NODES * HID2 * 2;
    unsigned short* agg2b = (unsigned short*)p; p += (size_t)N_NODES * HID2 * 2;

    // Graph preprocessing (2 launches)
    hist_scan_kernel<<<1, 1024, 0, stream>>>(ei, deg, row_ptr, cnt);
    fill_kernel<<<N_EDGES / 256, 256, 0, stream>>>(ei, deg, row_ptr, cnt, csr_src, csr_w);

    // Conversions (xcvt + W1/W2 transpose in one launch)
    prep_kernel<<<10240, 256, 0, stream>>>(x, xb, W1, W1t, W2, W2t);

    // Layer 1
    agg1_kernel<<<N_NODES / 2, 256, 0, stream>>>(xb, row_ptr, csr_src, csr_w, deg, agg_x);
    gemm_mfma_kernel<true, true, true><<<(HID1 / 128) * (N_NODES / 128), 256, 0, stream>>>(
        agg_x, W1t, b1, h1, N_NODES, HID1, F_IN);

    // Layer 2
    gemm_mfma_kernel<true, false, false><<<(HID2 / 128) * (N_NODES / 128), 256, 0, stream>>>(
        h1, W2t, nullptr, h2pre, N_NODES, HID2, HID1);
    agg2_kernel<<<N_NODES, 256, 0, stream>>>(h2pre, row_ptr, csr_src, csr_w, deg, b2, agg2b);

    // Layer 3
    gemm3_mfma_kernel<<<N_NODES / 64, 256, 0, stream>>>(agg2b, W3, h3);
    final_kernel<<<N_NODES / 256, 256, 0, stream>>>(h3, row_ptr, csr_src, csr_w, deg, b3, out);
}